// Round 1
// baseline (128.969 us; speedup 1.0000x reference)
//
#include <hip/hip_runtime.h>

// Part_CAM: only parts e=1..4 survive feat_cam[:,1:].
// Row-0-of-chain trick: e0^T * (sub[11] @ ... @ sub[0]) via 12 vec-mat products.
//
// parts (e=1..4): (s,t) = (5,201), (5,103), (54,152), (103,201)
//   idx = [e] ++ [s..t-1], M = t-s+1  (197, 99, 99, 99)

#define L_ 12
#define B_ 64
#define N_ 201
#define D_ 768

__global__ __launch_bounds__(256) void part_cam_kernel(
    const float* __restrict__ x,     // (L, B, N, N)
    const float* __restrict__ feat,  // (B, N, D)
    float* __restrict__ out)         // (B, 4, D)
{
    const int p = blockIdx.x >> 6;   // 0..3  (part e = p+1)
    const int b = blockIdx.x & 63;
    const int e = p + 1;
    const int s = (p == 0) ? 5 : (p == 1) ? 5 : (p == 2) ? 54 : 103;
    const int t = (p == 0) ? 201 : (p == 1) ? 103 : (p == 2) ? 152 : 201;
    const int K = t - s;
    const int M = K + 1;
    const int tid = threadIdx.x;

    __shared__ float bufA[200];
    __shared__ float bufB[200];
    float* vin  = bufA;
    float* vout = bufB;

    const size_t mat_elems = (size_t)N_ * N_;
    // column this thread owns: idx[tid]
    const int mycol = (tid == 0) ? e : (s + tid - 1);

    // v = row 0 of sub[11]  (pure row gather, no reduction)
    if (tid < M) {
        const float* m11 = x + ((size_t)11 * B_ + b) * mat_elems;
        vin[tid] = m11[(size_t)e * N_ + mycol];
    }
    __syncthreads();

    // v <- v * sub[l]  for l = 10 .. 0
    for (int l = 10; l >= 0; --l) {
        const float* mat = x + ((size_t)l * B_ + b) * mat_elems;
        if (tid < M) {
            // r = 0 row is idx[0] = e
            float acc = vin[0] * mat[(size_t)e * N_ + mycol];
            const float* rowp = mat + (size_t)s * N_ + mycol;
            #pragma unroll 8
            for (int r = 1; r < M; ++r) {
                acc += vin[r] * rowp[(size_t)(r - 1) * N_];
            }
            vout[tid] = acc;
        }
        __syncthreads();
        float* tmp = vin; vin = vout; vout = tmp;
    }

    // w[k] = vin[1+k], k = 0..K-1 ;  cam[d] = sum_k w[k] * relu(feat[b, s+k, d])
    const float* fb = feat + (size_t)b * N_ * D_;
    float a0 = 0.f, a1 = 0.f, a2 = 0.f;
    #pragma unroll 4
    for (int k = 0; k < K; ++k) {
        const float wk = vin[1 + k];
        const float* frow = fb + (size_t)(s + k) * D_;
        a0 += wk * fmaxf(frow[tid],        0.f);
        a1 += wk * fmaxf(frow[tid + 256],  0.f);
        a2 += wk * fmaxf(frow[tid + 512],  0.f);
    }
    float* orow = out + ((size_t)b * 4 + p) * D_;
    orow[tid]       = a0;
    orow[tid + 256] = a1;
    orow[tid + 512] = a2;
}

extern "C" void kernel_launch(void* const* d_in, const int* in_sizes, int n_in,
                              void* d_out, int out_size, void* d_ws, size_t ws_size,
                              hipStream_t stream) {
    const float* x    = (const float*)d_in[0];
    const float* feat = (const float*)d_in[1];
    float* out = (float*)d_out;
    part_cam_kernel<<<dim3(256), dim3(256), 0, stream>>>(x, feat, out);
}

// Round 2
// 75.990 us; speedup vs baseline: 1.6972x; 1.6972x over previous
//
#include <hip/hip_runtime.h>

// Part_CAM: only parts e=1..4 survive feat_cam[:,1:].
// Row-0-of-chain trick: e0^T * (sub[11] @ ... @ sub[0]) via 12 vec-mat products.
// This round: 1024-thread blocks; vecmat reduction split across row-groups
// (4x256 for M=197, 8x128 for M=99) to raise occupancy & memory parallelism.

#define L_ 12
#define B_ 64
#define N_ 201
#define D_ 768

__global__ __launch_bounds__(1024) void part_cam_kernel(
    const float* __restrict__ x,     // (L, B, N, N)
    const float* __restrict__ feat,  // (B, N, D)
    float* __restrict__ out)         // (B, 4, D)
{
    const int p = blockIdx.x >> 6;   // 0..3  (part e = p+1)
    const int b = blockIdx.x & 63;
    const int e = p + 1;
    const int s = (p == 0) ? 5 : (p == 1) ? 5 : (p == 2) ? 54 : 103;
    const int t = (p == 0) ? 201 : (p == 1) ? 103 : (p == 2) ? 152 : 201;
    const int K = t - s;
    const int M = K + 1;             // 197 or 99
    const int tid = threadIdx.x;

    // vec-mat layout: columns x row-groups
    const int CW  = (p == 0) ? 256 : 128;   // column width
    const int RGS = (p == 0) ? 4 : 8;       // row groups
    const int c   = tid & (CW - 1);
    const int rg  = tid / CW;
    const int rows_per = (M + RGS - 1) / RGS;   // 50 or 13
    const int r0 = rg * rows_per;
    const int r1 = (r0 + rows_per < M) ? (r0 + rows_per) : M;

    __shared__ float bufA[256];
    __shared__ float bufB[256];
    __shared__ float vpart[1024];
    __shared__ float eacc[4 * 768];

    float* vin  = bufA;
    float* vout = bufB;

    const size_t mat_elems = (size_t)N_ * N_;
    const int mycol = (c == 0) ? e : (s + c - 1);   // idx[c]

    // v = row 0 of sub[11]  (row gather)
    if (tid < M) {
        const float* m11 = x + ((size_t)11 * B_ + b) * mat_elems;
        vin[tid] = m11[(size_t)e * N_ + ((tid == 0) ? e : (s + tid - 1))];
    }
    __syncthreads();

    // v <- v * sub[l]  for l = 10 .. 0, row-split + LDS reduce
    for (int l = 10; l >= 0; --l) {
        const float* mat = x + ((size_t)l * B_ + b) * mat_elems;
        float acc = 0.f;
        if (c < M) {
            const float* colp = mat + mycol;
            int r = r0;
            if (r == 0) { acc = vin[0] * colp[(size_t)e * N_]; r = 1; }
            #pragma unroll 4
            for (; r < r1; ++r) {
                acc += vin[r] * colp[(size_t)(s + r - 1) * N_];
            }
        }
        vpart[tid] = acc;            // == vpart[rg*CW + c]
        __syncthreads();
        if (tid < M) {
            float sum = 0.f;
            #pragma unroll
            for (int g = 0; g < 8; ++g) {
                if (g < RGS) sum += vpart[g * CW + tid];
            }
            vout[tid] = sum;
        }
        __syncthreads();
        float* tmp = vin; vin = vout; vout = tmp;
    }

    // epilogue: cam[d] = sum_k v[1+k] * relu(feat[b, s+k, d]), k-split 4 ways
    const float* fb = feat + (size_t)b * N_ * D_;
    const int ed = tid & 255;
    const int eg = tid >> 8;              // 0..3
    const int kpg = (K + 3) >> 2;
    const int k0 = eg * kpg;
    const int k1 = (k0 + kpg < K) ? (k0 + kpg) : K;
    float a0 = 0.f, a1 = 0.f, a2 = 0.f;
    #pragma unroll 2
    for (int k = k0; k < k1; ++k) {
        const float wk = vin[1 + k];
        const float* frow = fb + (size_t)(s + k) * D_;
        a0 += wk * fmaxf(frow[ed],       0.f);
        a1 += wk * fmaxf(frow[ed + 256], 0.f);
        a2 += wk * fmaxf(frow[ed + 512], 0.f);
    }
    eacc[eg * 768 + ed]       = a0;
    eacc[eg * 768 + ed + 256] = a1;
    eacc[eg * 768 + ed + 512] = a2;
    __syncthreads();
    if (tid < 768) {
        float sum = eacc[tid] + eacc[768 + tid] + eacc[1536 + tid] + eacc[2304 + tid];
        out[((size_t)b * 4 + p) * D_ + tid] = sum;
    }
}

extern "C" void kernel_launch(void* const* d_in, const int* in_sizes, int n_in,
                              void* d_out, int out_size, void* d_ws, size_t ws_size,
                              hipStream_t stream) {
    const float* x    = (const float*)d_in[0];
    const float* feat = (const float*)d_in[1];
    float* out = (float*)d_out;
    part_cam_kernel<<<dim3(256), dim3(1024), 0, stream>>>(x, feat, out);
}